// Round 5
// baseline (920.448 us; speedup 1.0000x reference)
//
// ENVIRONMENT-PROBE ROUND: this is the exact kernel that PASSED round 0 of this
// session (914 us, absmax 0.015625). Rounds 1-4 failed with mutually inconsistent
// absmax values including a round bit-identical to this one; resubmitting the
// verified baseline to distinguish harness/container flakiness from code bugs.
#include <hip/hip_runtime.h>
#include <math.h>

#define NN    16384
#define NB    8
#define HD    128
#define TILE  32
#define HALO  6
#define RWS   44      // TILE + 2*HALO (valid rows)
#define RWSP  48      // padded to 3 m-tiles of 16
#define PITCH 132     // fp32 row pitch: 528 B = 16B-aligned; bank stride 132%32=4

typedef short v8s __attribute__((ext_vector_type(8)));
typedef float v4f __attribute__((ext_vector_type(4)));

__device__ __forceinline__ unsigned short f2b(float x) {
  union { float f; unsigned u; } v; v.f = x;
  unsigned r = v.u + 0x7FFFu + ((v.u >> 16) & 1u);
  return (unsigned short)(r >> 16);
}
__device__ __forceinline__ float b2f(unsigned short u) {
  union { unsigned u; float f; } v; v.u = ((unsigned)u) << 16; return v.f;
}
__device__ __forceinline__ float silu_acc(float z) {
  return z / (1.0f + expf(-z));   // accurate libm path (validated in round 4)
}
// split 8 fp32 -> bf16 hi + bf16 residual lo (x ~= hi + lo, rel err ~2^-17)
__device__ __forceinline__ void split8(const float* p, v8s& hi, v8s& lo) {
#pragma unroll
  for (int j = 0; j < 8; ++j) {
    unsigned short u = f2b(p[j]);
    hi[j] = (short)u;
    lo[j] = (short)f2b(p[j] - b2f(u));
  }
}

// MFMA GEMM, bf16x3 (fp32-quality): acc[mt][nt] += X[MOFF+mt*16+m][:] @ W[:][n]
// X: fp32 in LDS (PITCH row pitch). W: fp32 in GLOBAL, row-major [128][128] (k-major
// rows) -- exactly the layout the B-operand wants, no transpose.
// Wave covers output cols [wave*32, wave*32+32).
template<int MT, int MOFF>
__device__ __forceinline__ void mgemm(const float* X, const float* __restrict__ W,
                                      int wave, int l15, int quad, v4f acc[][2]) {
  const int k0q = quad * 8;
  v8s whi[2][4], wlo[2][4];
#pragma unroll
  for (int nt = 0; nt < 2; ++nt) {
    const int n = wave * 32 + nt * 16 + l15;
#pragma unroll
    for (int ks = 0; ks < 4; ++ks) {
      float wv[8];
#pragma unroll
      for (int j = 0; j < 8; ++j) wv[j] = W[(ks * 32 + k0q + j) * HD + n];
      split8(wv, whi[nt][ks], wlo[nt][ks]);
    }
  }
#pragma unroll
  for (int ks = 0; ks < 4; ++ks) {
#pragma unroll
    for (int mt = 0; mt < MT; ++mt) {
      float xv[8];
      const float* xp = &X[(MOFF + mt * 16 + l15) * PITCH + ks * 32 + k0q];
      *(float4*)&xv[0] = *(const float4*)xp;
      *(float4*)&xv[4] = *(const float4*)(xp + 4);
      v8s ahi, alo;
      split8(xv, ahi, alo);
#pragma unroll
      for (int nt = 0; nt < 2; ++nt) {
        acc[mt][nt] = __builtin_amdgcn_mfma_f32_16x16x32_bf16(ahi, whi[nt][ks], acc[mt][nt], 0, 0, 0);
        acc[mt][nt] = __builtin_amdgcn_mfma_f32_16x16x32_bf16(ahi, wlo[nt][ks], acc[mt][nt], 0, 0, 0);
        acc[mt][nt] = __builtin_amdgcn_mfma_f32_16x16x32_bf16(alo, whi[nt][ks], acc[mt][nt], 0, 0, 0);
      }
    }
  }
}

__global__ __launch_bounds__(256, 2) void gno_mfma(
    const float* __restrict__ h, const float* __restrict__ coord,
    const float* __restrict__ msg_w1, const float* __restrict__ msg_b1,
    const float* __restrict__ msg_w2, const float* __restrict__ msg_b2,
    const float* __restrict__ upd_w1, const float* __restrict__ upd_b1,
    const float* __restrict__ upd_w2, const float* __restrict__ upd_b2,
    const float* __restrict__ ln_g, const float* __restrict__ ln_b,
    float* __restrict__ out) {
  __shared__ float sH[RWSP * PITCH];  // h fp32, rows = nodes n0-6 .. n0+41 (44..47 zero/extra)
  __shared__ float sB[RWSP * PITCH];  // B (G1->MSG), then agg rows 0..31 (G3->G4)
  __shared__ float sA[TILE * PITCH];  // A (G2->MSG), then t (G4->G5)
  __shared__ float sS[TILE * PITCH];  // s (MSG->G3), then dh (G5->LN)
  __shared__ float sC[RWSP];          // coord

  const int t = threadIdx.x;
  const int wave = t >> 6, lane = t & 63, l15 = lane & 15, quad = lane >> 4;
  const int b = blockIdx.x / (NN / TILE);
  const int n0 = (blockIdx.x % (NN / TILE)) * TILE;
  const size_t hb = ((size_t)b * NN + n0) * HD;
  const int col0 = wave * 32 + l15, col1 = col0 + 16;

  // ---- stage h + coord (fp32), zero-fill OOB rows; 48 rows for m-tile alignment ----
  for (int e = t; e < RWSP * HD; e += 256) {
    int r = e >> 7, cc = e & 127;
    int g = n0 - HALO + r;
    sH[r * PITCH + cc] = (g >= 0 && g < NN) ? h[((size_t)b * NN + g) * HD + cc] : 0.f;
  }
  if (t < RWSP) {
    int g = n0 - HALO + t;
    sC[t] = (g >= 0 && g < NN) ? coord[(size_t)b * NN + g] : 0.f;
  }
  __syncthreads();

  // ---- G1 (MFMA): B = sH(48 rows) @ msg_w1[128:256] -> sB ----
  {
    v4f acc[3][2];
#pragma unroll
    for (int mt = 0; mt < 3; ++mt)
#pragma unroll
      for (int nt = 0; nt < 2; ++nt) acc[mt][nt] = (v4f){0.f, 0.f, 0.f, 0.f};
    mgemm<3, 0>(sH, msg_w1 + 128 * HD, wave, l15, quad, acc);
#pragma unroll
    for (int mt = 0; mt < 3; ++mt)
#pragma unroll
      for (int nt = 0; nt < 2; ++nt)
#pragma unroll
        for (int rg = 0; rg < 4; ++rg)
          sB[(mt * 16 + quad * 4 + rg) * PITCH + wave * 32 + nt * 16 + l15] = acc[mt][nt][rg];
  }
  // ---- G2 (MFMA): A = sH(tile rows) @ msg_w1[0:128] + b1 -> sA ----
  {
    v4f acc[2][2];
#pragma unroll
    for (int mt = 0; mt < 2; ++mt)
#pragma unroll
      for (int nt = 0; nt < 2; ++nt) acc[mt][nt] = (v4f){0.f, 0.f, 0.f, 0.f};
    mgemm<2, HALO>(sH, msg_w1, wave, l15, quad, acc);
    float bv0 = msg_b1[col0], bv1 = msg_b1[col1];
#pragma unroll
    for (int mt = 0; mt < 2; ++mt)
#pragma unroll
      for (int nt = 0; nt < 2; ++nt)
#pragma unroll
        for (int rg = 0; rg < 4; ++rg)
          sA[(mt * 16 + quad * 4 + rg) * PITCH + wave * 32 + nt * 16 + l15] =
              acc[mt][nt][rg] + (nt ? bv1 : bv0);
  }
  __syncthreads();

  // ---- MSG (verbatim round 4): s_i = (1/cnt) * sum silu(A_i + B_j + dc*w1_last) ----
  {
    const int c = t & 127;
    const int half = t >> 7;
    const float wl = msg_w1[256 * HD + c];
    for (int rr = 0; rr < 16; ++rr) {
      const int r = half * 16 + rr;
      const int i = n0 + r;
      const float a = sA[r * PITCH + c];
      const float ci = sC[r + HALO];
      float s = 0.f;
#pragma unroll
      for (int d = -HALO; d <= HALO; ++d) {
        if (d == 0) continue;
        const int j = i + d;
        if (j >= 0 && j < NN) {
          const int rj = r + HALO + d;
          const float z = a + sB[rj * PITCH + c] + (sC[rj] - ci) * wl;
          s += silu_acc(z);
        }
      }
      const int cnt = min(i, HALO) + min(NN - 1 - i, HALO);
      sS[r * PITCH + c] = s / (float)cnt;
    }
  }
  __syncthreads();

  // ---- G3 (MFMA): agg = sS @ msg_w2 + b2 -> sB rows 0..31 (B dead) ----
  {
    v4f acc[2][2];
#pragma unroll
    for (int mt = 0; mt < 2; ++mt)
#pragma unroll
      for (int nt = 0; nt < 2; ++nt) acc[mt][nt] = (v4f){0.f, 0.f, 0.f, 0.f};
    mgemm<2, 0>(sS, msg_w2, wave, l15, quad, acc);
    float bv0 = msg_b2[col0], bv1 = msg_b2[col1];
    __syncthreads();
#pragma unroll
    for (int mt = 0; mt < 2; ++mt)
#pragma unroll
      for (int nt = 0; nt < 2; ++nt)
#pragma unroll
        for (int rg = 0; rg < 4; ++rg)
          sB[(mt * 16 + quad * 4 + rg) * PITCH + wave * 32 + nt * 16 + l15] =
              acc[mt][nt][rg] + (nt ? bv1 : bv0);
  }
  __syncthreads();

  // ---- G4 (MFMA): t = silu(sH@upd_w1[0:128] + agg@upd_w1[128:256] + ub1) -> sA ----
  {
    v4f acc[2][2];
#pragma unroll
    for (int mt = 0; mt < 2; ++mt)
#pragma unroll
      for (int nt = 0; nt < 2; ++nt) acc[mt][nt] = (v4f){0.f, 0.f, 0.f, 0.f};
    mgemm<2, HALO>(sH, upd_w1, wave, l15, quad, acc);
    mgemm<2, 0>(sB, upd_w1 + 128 * HD, wave, l15, quad, acc);
    float bv0 = upd_b1[col0], bv1 = upd_b1[col1];
#pragma unroll
    for (int mt = 0; mt < 2; ++mt)
#pragma unroll
      for (int nt = 0; nt < 2; ++nt)
#pragma unroll
        for (int rg = 0; rg < 4; ++rg)
          sA[(mt * 16 + quad * 4 + rg) * PITCH + wave * 32 + nt * 16 + l15] =
              silu_acc(acc[mt][nt][rg] + (nt ? bv1 : bv0));
  }
  __syncthreads();

  // ---- G5 (MFMA): dh = t @ upd_w2 + ub2 -> sS (s dead) ----
  {
    v4f acc[2][2];
#pragma unroll
    for (int mt = 0; mt < 2; ++mt)
#pragma unroll
      for (int nt = 0; nt < 2; ++nt) acc[mt][nt] = (v4f){0.f, 0.f, 0.f, 0.f};
    mgemm<2, 0>(sA, upd_w2, wave, l15, quad, acc);
    float bv0 = upd_b2[col0], bv1 = upd_b2[col1];
#pragma unroll
    for (int mt = 0; mt < 2; ++mt)
#pragma unroll
      for (int nt = 0; nt < 2; ++nt)
#pragma unroll
        for (int rg = 0; rg < 4; ++rg)
          sS[(mt * 16 + quad * 4 + rg) * PITCH + wave * 32 + nt * 16 + l15] =
              acc[mt][nt][rg] + (nt ? bv1 : bv0);
  }
  __syncthreads();

  // ---- LN (verbatim round 4): x = h + dh; out = (x-mu)*rstd*g + b ----
  {
    const int r = t >> 3;       // 0..31
    const int part = t & 7;     // 0..7
    const int c0 = part * 16;
    const float* hrow = h + hb + (size_t)r * HD + c0;
    float xs[16];
    float s1 = 0.f, s2 = 0.f;
#pragma unroll
    for (int q = 0; q < 4; ++q) {
      float4 hv = *(const float4*)(hrow + q * 4);
      float4 dv = *(const float4*)&sS[r * PITCH + c0 + q * 4];
      float x0 = hv.x + dv.x, x1 = hv.y + dv.y, x2 = hv.z + dv.z, x3 = hv.w + dv.w;
      xs[q * 4 + 0] = x0; xs[q * 4 + 1] = x1; xs[q * 4 + 2] = x2; xs[q * 4 + 3] = x3;
      s1 += x0 + x1 + x2 + x3;
      s2 += x0 * x0 + x1 * x1 + x2 * x2 + x3 * x3;
    }
    s1 += __shfl_xor(s1, 1); s2 += __shfl_xor(s2, 1);
    s1 += __shfl_xor(s1, 2); s2 += __shfl_xor(s2, 2);
    s1 += __shfl_xor(s1, 4); s2 += __shfl_xor(s2, 4);
    float mean = s1 * (1.0f / 128.0f);
    float var = s2 * (1.0f / 128.0f) - mean * mean;
    float rstd = rsqrtf(fmaxf(var, 0.f) + 1e-5f);
    float* orow = out + hb + (size_t)r * HD + c0;
#pragma unroll
    for (int q = 0; q < 4; ++q) {
      float4 gv = *(const float4*)(ln_g + c0 + q * 4);
      float4 bv = *(const float4*)(ln_b + c0 + q * 4);
      float4 ov;
      ov.x = (xs[q * 4 + 0] - mean) * rstd * gv.x + bv.x;
      ov.y = (xs[q * 4 + 1] - mean) * rstd * gv.y + bv.y;
      ov.z = (xs[q * 4 + 2] - mean) * rstd * gv.z + bv.z;
      ov.w = (xs[q * 4 + 3] - mean) * rstd * gv.w + bv.w;
      *(float4*)(orow + q * 4) = ov;
    }
  }
}

extern "C" void kernel_launch(void* const* d_in, const int* in_sizes, int n_in,
                              void* d_out, int out_size, void* d_ws, size_t ws_size,
                              hipStream_t stream) {
  const float* h      = (const float*)d_in[0];
  const float* coord  = (const float*)d_in[1];
  const float* msg_w1 = (const float*)d_in[2];
  const float* msg_b1 = (const float*)d_in[3];
  const float* msg_w2 = (const float*)d_in[4];
  const float* msg_b2 = (const float*)d_in[5];
  const float* upd_w1 = (const float*)d_in[6];
  const float* upd_b1 = (const float*)d_in[7];
  const float* upd_w2 = (const float*)d_in[8];
  const float* upd_b2 = (const float*)d_in[9];
  const float* ln_g   = (const float*)d_in[10];
  const float* ln_b   = (const float*)d_in[11];

  gno_mfma<<<NB * (NN / TILE), 256, 0, stream>>>(
      h, coord, msg_w1, msg_b1, msg_w2, msg_b2, upd_w1, upd_b1, upd_w2, upd_b2,
      ln_g, ln_b, (float*)d_out);
}

// Round 6
// 727.630 us; speedup vs baseline: 1.2650x; 1.2650x over previous
//
// TILE=64 / 512-thread variant: doubles waves/SIMD (1 -> 2) while keeping the
// empirically-safe round-0 structure: separate sH/sB/sA/sS/sC buffers, no
// in-place LDS reuse, exactly 1 workgroup/CU (LDS 152 KB of 160 KB).
// Per-element arithmetic bit-identical to the passing round-0/5 kernel.
#include <hip/hip_runtime.h>
#include <math.h>

#define NN    16384
#define NB    8
#define HD    128
#define TILE  64
#define HALO  6
#define RWS   76      // TILE + 2*HALO (valid rows)
#define RWSP  80      // padded to 5 m-tiles of 16
#define PITCH 132     // fp32 row pitch: 528 B = 16B-aligned; bank stride 132%32=4

typedef short v8s __attribute__((ext_vector_type(8)));
typedef float v4f __attribute__((ext_vector_type(4)));

__device__ __forceinline__ unsigned short f2b(float x) {
  union { float f; unsigned u; } v; v.f = x;
  unsigned r = v.u + 0x7FFFu + ((v.u >> 16) & 1u);
  return (unsigned short)(r >> 16);
}
__device__ __forceinline__ float b2f(unsigned short u) {
  union { unsigned u; float f; } v; v.u = ((unsigned)u) << 16; return v.f;
}
__device__ __forceinline__ float silu_acc(float z) {
  return z / (1.0f + expf(-z));   // accurate libm path (validated rounds 0/5)
}
// split 8 fp32 -> bf16 hi + bf16 residual lo (x ~= hi + lo, rel err ~2^-17)
__device__ __forceinline__ void split8(const float* p, v8s& hi, v8s& lo) {
#pragma unroll
  for (int j = 0; j < 8; ++j) {
    unsigned short u = f2b(p[j]);
    hi[j] = (short)u;
    lo[j] = (short)f2b(p[j] - b2f(u));
  }
}

// MFMA GEMM, bf16x3 (fp32-quality): acc[mt][nt] += X[moff+mt*16+m][:] @ W[:][n]
// X: fp32 in LDS (PITCH row pitch). W: fp32 in GLOBAL, row-major [128][128].
// Wave covers output cols [wn*32, wn*32+32).  moff is a runtime row offset
// (was a template arg in round 0; arithmetic unchanged).
template<int MT>
__device__ __forceinline__ void mgemm(const float* X, const float* __restrict__ W,
                                      int moff, int wn, int l15, int quad, v4f acc[][2]) {
  const int k0q = quad * 8;
  v8s whi[2][4], wlo[2][4];
#pragma unroll
  for (int nt = 0; nt < 2; ++nt) {
    const int n = wn * 32 + nt * 16 + l15;
#pragma unroll
    for (int ks = 0; ks < 4; ++ks) {
      float wv[8];
#pragma unroll
      for (int j = 0; j < 8; ++j) wv[j] = W[(ks * 32 + k0q + j) * HD + n];
      split8(wv, whi[nt][ks], wlo[nt][ks]);
    }
  }
#pragma unroll
  for (int ks = 0; ks < 4; ++ks) {
#pragma unroll
    for (int mt = 0; mt < MT; ++mt) {
      float xv[8];
      const float* xp = &X[(moff + mt * 16 + l15) * PITCH + ks * 32 + k0q];
      *(float4*)&xv[0] = *(const float4*)xp;
      *(float4*)&xv[4] = *(const float4*)(xp + 4);
      v8s ahi, alo;
      split8(xv, ahi, alo);
#pragma unroll
      for (int nt = 0; nt < 2; ++nt) {
        acc[mt][nt] = __builtin_amdgcn_mfma_f32_16x16x32_bf16(ahi, whi[nt][ks], acc[mt][nt], 0, 0, 0);
        acc[mt][nt] = __builtin_amdgcn_mfma_f32_16x16x32_bf16(ahi, wlo[nt][ks], acc[mt][nt], 0, 0, 0);
        acc[mt][nt] = __builtin_amdgcn_mfma_f32_16x16x32_bf16(alo, whi[nt][ks], acc[mt][nt], 0, 0, 0);
      }
    }
  }
}

__global__ __launch_bounds__(512, 2) void gno_mfma(
    const float* __restrict__ h, const float* __restrict__ coord,
    const float* __restrict__ msg_w1, const float* __restrict__ msg_b1,
    const float* __restrict__ msg_w2, const float* __restrict__ msg_b2,
    const float* __restrict__ upd_w1, const float* __restrict__ upd_b1,
    const float* __restrict__ upd_w2, const float* __restrict__ upd_b2,
    const float* __restrict__ ln_g, const float* __restrict__ ln_b,
    float* __restrict__ out) {
  // LDS = 42240 + 42240 + 33792 + 33792 + 320 = 152384 B -> 1 WG/CU, 8 waves
  __shared__ float sH[RWSP * PITCH];  // h fp32, rows = nodes n0-6 .. n0+69 (76..79 zero)
  __shared__ float sB[RWSP * PITCH];  // B (G1->MSG), then agg rows 0..63 (G3->G4)
  __shared__ float sA[TILE * PITCH];  // A (G2->MSG), then t (G4->G5)
  __shared__ float sS[TILE * PITCH];  // s (MSG->G3), then dh (G5->LN)
  __shared__ float sC[RWSP];          // coord

  const int t = threadIdx.x;
  const int wave = t >> 6, lane = t & 63, l15 = lane & 15, quad = lane >> 4;
  const int wn = wave & 3;            // column group: cols [wn*32, wn*32+32)
  const int wm = wave >> 2;           // row group: rows [wm*32, wm*32+32) of the tile
  const int b = blockIdx.x / (NN / TILE);
  const int n0 = (blockIdx.x % (NN / TILE)) * TILE;
  const size_t hb = ((size_t)b * NN + n0) * HD;
  const int col0 = wn * 32 + l15, col1 = col0 + 16;

  // ---- stage h + coord (fp32), zero-fill OOB rows; 80 rows for m-tile alignment ----
  for (int e = t; e < RWSP * HD; e += 512) {
    int r = e >> 7, cc = e & 127;
    int g = n0 - HALO + r;
    sH[r * PITCH + cc] = (g >= 0 && g < NN) ? h[((size_t)b * NN + g) * HD + cc] : 0.f;
  }
  if (t < RWSP) {
    int g = n0 - HALO + t;
    sC[t] = (g >= 0 && g < NN) ? coord[(size_t)b * NN + g] : 0.f;
  }
  __syncthreads();

  // ---- G1 (MFMA): B = sH(80 rows) @ msg_w1[128:256] -> sB ----
  // wm=0 covers m-tiles 0..2 (rows 0..47), wm=1 covers m-tiles 3..4 (rows 48..79).
  if (wm == 0) {
    v4f acc[3][2];
#pragma unroll
    for (int mt = 0; mt < 3; ++mt)
#pragma unroll
      for (int nt = 0; nt < 2; ++nt) acc[mt][nt] = (v4f){0.f, 0.f, 0.f, 0.f};
    mgemm<3>(sH, msg_w1 + 128 * HD, 0, wn, l15, quad, acc);
#pragma unroll
    for (int mt = 0; mt < 3; ++mt)
#pragma unroll
      for (int nt = 0; nt < 2; ++nt)
#pragma unroll
        for (int rg = 0; rg < 4; ++rg)
          sB[(mt * 16 + quad * 4 + rg) * PITCH + wn * 32 + nt * 16 + l15] = acc[mt][nt][rg];
  } else {
    v4f acc[2][2];
#pragma unroll
    for (int mt = 0; mt < 2; ++mt)
#pragma unroll
      for (int nt = 0; nt < 2; ++nt) acc[mt][nt] = (v4f){0.f, 0.f, 0.f, 0.f};
    mgemm<2>(sH, msg_w1 + 128 * HD, 48, wn, l15, quad, acc);
#pragma unroll
    for (int mt = 0; mt < 2; ++mt)
#pragma unroll
      for (int nt = 0; nt < 2; ++nt)
#pragma unroll
        for (int rg = 0; rg < 4; ++rg)
          sB[(48 + mt * 16 + quad * 4 + rg) * PITCH + wn * 32 + nt * 16 + l15] = acc[mt][nt][rg];
  }
  // ---- G2 (MFMA): A = sH(tile rows) @ msg_w1[0:128] + b1 -> sA ----
  {
    v4f acc[2][2];
#pragma unroll
    for (int mt = 0; mt < 2; ++mt)
#pragma unroll
      for (int nt = 0; nt < 2; ++nt) acc[mt][nt] = (v4f){0.f, 0.f, 0.f, 0.f};
    mgemm<2>(sH, msg_w1, HALO + wm * 32, wn, l15, quad, acc);
    float bv0 = msg_b1[col0], bv1 = msg_b1[col1];
#pragma unroll
    for (int mt = 0; mt < 2; ++mt)
#pragma unroll
      for (int nt = 0; nt < 2; ++nt)
#pragma unroll
        for (int rg = 0; rg < 4; ++rg)
          sA[(wm * 32 + mt * 16 + quad * 4 + rg) * PITCH + wn * 32 + nt * 16 + l15] =
              acc[mt][nt][rg] + (nt ? bv1 : bv0);
  }
  __syncthreads();

  // ---- MSG (verbatim math): s_i = (1/cnt) * sum silu(A_i + B_j + dc*w1_last) ----
  {
    const int c = t & 127;
    const int grp = t >> 7;   // 0..3 -> rows grp*16 .. grp*16+15
    const float wl = msg_w1[256 * HD + c];
    for (int rr = 0; rr < 16; ++rr) {
      const int r = grp * 16 + rr;
      const int i = n0 + r;
      const float a = sA[r * PITCH + c];
      const float ci = sC[r + HALO];
      float s = 0.f;
#pragma unroll
      for (int d = -HALO; d <= HALO; ++d) {
        if (d == 0) continue;
        const int j = i + d;
        if (j >= 0 && j < NN) {
          const int rj = r + HALO + d;
          const float z = a + sB[rj * PITCH + c] + (sC[rj] - ci) * wl;
          s += silu_acc(z);
        }
      }
      const int cnt = min(i, HALO) + min(NN - 1 - i, HALO);
      sS[r * PITCH + c] = s / (float)cnt;
    }
  }
  __syncthreads();

  // ---- G3 (MFMA): agg = sS @ msg_w2 + b2 -> sB rows 0..63 (B dead) ----
  {
    v4f acc[2][2];
#pragma unroll
    for (int mt = 0; mt < 2; ++mt)
#pragma unroll
      for (int nt = 0; nt < 2; ++nt) acc[mt][nt] = (v4f){0.f, 0.f, 0.f, 0.f};
    mgemm<2>(sS, msg_w2, wm * 32, wn, l15, quad, acc);
    float bv0 = msg_b2[col0], bv1 = msg_b2[col1];
    __syncthreads();
#pragma unroll
    for (int mt = 0; mt < 2; ++mt)
#pragma unroll
      for (int nt = 0; nt < 2; ++nt)
#pragma unroll
        for (int rg = 0; rg < 4; ++rg)
          sB[(wm * 32 + mt * 16 + quad * 4 + rg) * PITCH + wn * 32 + nt * 16 + l15] =
              acc[mt][nt][rg] + (nt ? bv1 : bv0);
  }
  __syncthreads();

  // ---- G4 (MFMA): t = silu(sH@upd_w1[0:128] + agg@upd_w1[128:256] + ub1) -> sA ----
  {
    v4f acc[2][2];
#pragma unroll
    for (int mt = 0; mt < 2; ++mt)
#pragma unroll
      for (int nt = 0; nt < 2; ++nt) acc[mt][nt] = (v4f){0.f, 0.f, 0.f, 0.f};
    mgemm<2>(sH, upd_w1, HALO + wm * 32, wn, l15, quad, acc);
    mgemm<2>(sB, upd_w1 + 128 * HD, wm * 32, wn, l15, quad, acc);
    float bv0 = upd_b1[col0], bv1 = upd_b1[col1];
#pragma unroll
    for (int mt = 0; mt < 2; ++mt)
#pragma unroll
      for (int nt = 0; nt < 2; ++nt)
#pragma unroll
        for (int rg = 0; rg < 4; ++rg)
          sA[(wm * 32 + mt * 16 + quad * 4 + rg) * PITCH + wn * 32 + nt * 16 + l15] =
              silu_acc(acc[mt][nt][rg] + (nt ? bv1 : bv0));
  }
  __syncthreads();

  // ---- G5 (MFMA): dh = t @ upd_w2 + ub2 -> sS (s dead) ----
  {
    v4f acc[2][2];
#pragma unroll
    for (int mt = 0; mt < 2; ++mt)
#pragma unroll
      for (int nt = 0; nt < 2; ++nt) acc[mt][nt] = (v4f){0.f, 0.f, 0.f, 0.f};
    mgemm<2>(sA, upd_w2, wm * 32, wn, l15, quad, acc);
    float bv0 = upd_b2[col0], bv1 = upd_b2[col1];
#pragma unroll
    for (int mt = 0; mt < 2; ++mt)
#pragma unroll
      for (int nt = 0; nt < 2; ++nt)
#pragma unroll
        for (int rg = 0; rg < 4; ++rg)
          sS[(wm * 32 + mt * 16 + quad * 4 + rg) * PITCH + wn * 32 + nt * 16 + l15] =
              acc[mt][nt][rg] + (nt ? bv1 : bv0);
  }
  __syncthreads();

  // ---- LN (verbatim math): x = h + dh; out = (x-mu)*rstd*g + b ----
  {
    const int r = t >> 3;       // 0..63
    const int part = t & 7;     // 0..7
    const int c0 = part * 16;
    const float* hrow = h + hb + (size_t)r * HD + c0;
    float xs[16];
    float s1 = 0.f, s2 = 0.f;
#pragma unroll
    for (int q = 0; q < 4; ++q) {
      float4 hv = *(const float4*)(hrow + q * 4);
      float4 dv = *(const float4*)&sS[r * PITCH + c0 + q * 4];
      float x0 = hv.x + dv.x, x1 = hv.y + dv.y, x2 = hv.z + dv.z, x3 = hv.w + dv.w;
      xs[q * 4 + 0] = x0; xs[q * 4 + 1] = x1; xs[q * 4 + 2] = x2; xs[q * 4 + 3] = x3;
      s1 += x0 + x1 + x2 + x3;
      s2 += x0 * x0 + x1 * x1 + x2 * x2 + x3 * x3;
    }
    s1 += __shfl_xor(s1, 1); s2 += __shfl_xor(s2, 1);
    s1 += __shfl_xor(s1, 2); s2 += __shfl_xor(s2, 2);
    s1 += __shfl_xor(s1, 4); s2 += __shfl_xor(s2, 4);
    float mean = s1 * (1.0f / 128.0f);
    float var = s2 * (1.0f / 128.0f) - mean * mean;
    float rstd = rsqrtf(fmaxf(var, 0.f) + 1e-5f);
    float* orow = out + hb + (size_t)r * HD + c0;
#pragma unroll
    for (int q = 0; q < 4; ++q) {
      float4 gv = *(const float4*)(ln_g + c0 + q * 4);
      float4 bv = *(const float4*)(ln_b + c0 + q * 4);
      float4 ov;
      ov.x = (xs[q * 4 + 0] - mean) * rstd * gv.x + bv.x;
      ov.y = (xs[q * 4 + 1] - mean) * rstd * gv.y + bv.y;
      ov.z = (xs[q * 4 + 2] - mean) * rstd * gv.z + bv.z;
      ov.w = (xs[q * 4 + 3] - mean) * rstd * gv.w + bv.w;
      *(float4*)(orow + q * 4) = ov;
    }
  }
}

extern "C" void kernel_launch(void* const* d_in, const int* in_sizes, int n_in,
                              void* d_out, int out_size, void* d_ws, size_t ws_size,
                              hipStream_t stream) {
  const float* h      = (const float*)d_in[0];
  const float* coord  = (const float*)d_in[1];
  const float* msg_w1 = (const float*)d_in[2];
  const float* msg_b1 = (const float*)d_in[3];
  const float* msg_w2 = (const float*)d_in[4];
  const float* msg_b2 = (const float*)d_in[5];
  const float* upd_w1 = (const float*)d_in[6];
  const float* upd_b1 = (const float*)d_in[7];
  const float* upd_w2 = (const float*)d_in[8];
  const float* upd_b2 = (const float*)d_in[9];
  const float* ln_g   = (const float*)d_in[10];
  const float* ln_b   = (const float*)d_in[11];

  gno_mfma<<<NB * (NN / TILE), 512, 0, stream>>>(
      h, coord, msg_w1, msg_b1, msg_w2, msg_b2, upd_w1, upd_b1, upd_w2, upd_b2,
      ln_g, ln_b, (float*)d_out);
}

// Round 7
// 527.390 us; speedup vs baseline: 1.7453x; 1.3797x over previous
//
// TILE=64 / 512-thread, pre-split bf16 hi/lo X-operand planes in LDS.
// MFMA operand bits identical to round 6; X-splits done ONCE at producer-write
// time instead of per-consumer (was 4x-redundant across column-waves).
// No type punning, no in-place RMW; buffer reuse only across barriers.
#include <hip/hip_runtime.h>
#include <math.h>

#define NN    16384
#define NB    8
#define HD    128
#define TILE  64
#define HALO  6
#define RWS   76      // TILE + 2*HALO (valid rows)
#define RWSP  80      // padded to 5 m-tiles of 16
#define PP    136     // bf16-plane pitch in shorts: 272 B/row, 16B-aligned
#define PB    132     // fp32 pitch (528 B = 16B-aligned)

typedef short v8s __attribute__((ext_vector_type(8)));
typedef float v4f __attribute__((ext_vector_type(4)));

__device__ __forceinline__ unsigned short f2b(float x) {
  union { float f; unsigned u; } v; v.f = x;
  unsigned r = v.u + 0x7FFFu + ((v.u >> 16) & 1u);
  return (unsigned short)(r >> 16);
}
__device__ __forceinline__ float b2f(unsigned short u) {
  union { unsigned u; float f; } v; v.u = ((unsigned)u) << 16; return v.f;
}
__device__ __forceinline__ float silu_acc(float z) {
  return z / (1.0f + expf(-z));   // accurate libm path (validated rounds 0/5/6)
}
// split 8 fp32 -> bf16 hi + bf16 residual lo (x ~= hi + lo, rel err ~2^-17)
__device__ __forceinline__ void split8(const float* p, v8s& hi, v8s& lo) {
#pragma unroll
  for (int j = 0; j < 8; ++j) {
    unsigned short u = f2b(p[j]);
    hi[j] = (short)u;
    lo[j] = (short)f2b(p[j] - b2f(u));
  }
}
// split value -> hi/lo planes (same arithmetic as split8, at producer-write time)
__device__ __forceinline__ void wr_pair(short* hiP, short* loP, int idx, float v) {
  unsigned short hb = f2b(v);
  hiP[idx] = (short)hb;
  loP[idx] = (short)f2b(v - b2f(hb));
}

// MFMA GEMM, bf16x3 (fp32-quality): acc[mt][nt] += X[moff+mt*16+m][:] @ W[:][n]
// X: pre-split bf16 hi/lo planes in LDS (pitch PP) -> 2x ds_read_b128, no conversion.
// W: fp32 in GLOBAL, row-major [128][128], split on the fly (round-6 path).
template<int MT>
__device__ __forceinline__ void mgemm(const short* Xhi, const short* Xlo,
                                      const float* __restrict__ W,
                                      int moff, int wn, int l15, int quad, v4f acc[][2]) {
  const int k0q = quad * 8;
  v8s whi[2][4], wlo[2][4];
#pragma unroll
  for (int nt = 0; nt < 2; ++nt) {
    const int n = wn * 32 + nt * 16 + l15;
#pragma unroll
    for (int ks = 0; ks < 4; ++ks) {
      float wv[8];
#pragma unroll
      for (int j = 0; j < 8; ++j) wv[j] = W[(ks * 32 + k0q + j) * HD + n];
      split8(wv, whi[nt][ks], wlo[nt][ks]);
    }
  }
#pragma unroll
  for (int ks = 0; ks < 4; ++ks) {
#pragma unroll
    for (int mt = 0; mt < MT; ++mt) {
      const int xo = (moff + mt * 16 + l15) * PP + ks * 32 + k0q;
      v8s ahi = *(const v8s*)&Xhi[xo];
      v8s alo = *(const v8s*)&Xlo[xo];
#pragma unroll
      for (int nt = 0; nt < 2; ++nt) {
        acc[mt][nt] = __builtin_amdgcn_mfma_f32_16x16x32_bf16(ahi, whi[nt][ks], acc[mt][nt], 0, 0, 0);
        acc[mt][nt] = __builtin_amdgcn_mfma_f32_16x16x32_bf16(ahi, wlo[nt][ks], acc[mt][nt], 0, 0, 0);
        acc[mt][nt] = __builtin_amdgcn_mfma_f32_16x16x32_bf16(alo, whi[nt][ks], acc[mt][nt], 0, 0, 0);
      }
    }
  }
}

__global__ __launch_bounds__(512, 2) void gno_mfma(
    const float* __restrict__ h, const float* __restrict__ coord,
    const float* __restrict__ msg_w1, const float* __restrict__ msg_b1,
    const float* __restrict__ msg_w2, const float* __restrict__ msg_b2,
    const float* __restrict__ upd_w1, const float* __restrict__ upd_b1,
    const float* __restrict__ upd_w2, const float* __restrict__ upd_b2,
    const float* __restrict__ ln_g, const float* __restrict__ ln_b,
    float* __restrict__ out) {
  // LDS = 43520 + 42240 + 34816 + 34816 + 320 = 155712 B -> 1 WG/CU, 8 waves
  __shared__ short sHhi[RWSP * PP], sHlo[RWSP * PP];    // h planes (G1,G2,G4)
  __shared__ float sBf[RWSP * PB];                      // B fp32 (G1->MSG), then dh fp32 (G5->LN)
  __shared__ short sP1hi[TILE * PP], sP1lo[TILE * PP];  // A (G2->MSG), then agg (G3->G4)
  __shared__ short sP2hi[TILE * PP], sP2lo[TILE * PP];  // s (MSG->G3), then t (G4->G5)
  __shared__ float sC[RWSP];                            // coord

  const int t = threadIdx.x;
  const int wave = t >> 6, lane = t & 63, l15 = lane & 15, quad = lane >> 4;
  const int wn = wave & 3;            // column group: cols [wn*32, wn*32+32)
  const int wm = wave >> 2;           // row group: rows [wm*32, wm*32+32) of the tile
  const int b = blockIdx.x / (NN / TILE);
  const int n0 = (blockIdx.x % (NN / TILE)) * TILE;
  const size_t hb = ((size_t)b * NN + n0) * HD;
  const int col0 = wn * 32 + l15, col1 = col0 + 16;

  // ---- stage h: split to bf16 hi/lo planes once; zero-fill OOB rows ----
  for (int e = t; e < RWSP * HD / 4; e += 512) {  // 2560 quads, 5 iters
    const int r = e >> 5, c4 = (e & 31) << 2;
    const int g = n0 - HALO + r;
    float4 v = {0.f, 0.f, 0.f, 0.f};
    if (g >= 0 && g < NN) v = *(const float4*)&h[((size_t)b * NN + g) * HD + c4];
    short4 h4, l4;
    { unsigned short u = f2b(v.x); h4.x = (short)u; l4.x = (short)f2b(v.x - b2f(u)); }
    { unsigned short u = f2b(v.y); h4.y = (short)u; l4.y = (short)f2b(v.y - b2f(u)); }
    { unsigned short u = f2b(v.z); h4.z = (short)u; l4.z = (short)f2b(v.z - b2f(u)); }
    { unsigned short u = f2b(v.w); h4.w = (short)u; l4.w = (short)f2b(v.w - b2f(u)); }
    *(short4*)&sHhi[r * PP + c4] = h4;
    *(short4*)&sHlo[r * PP + c4] = l4;
  }
  if (t < RWSP) {
    const int g = n0 - HALO + t;
    sC[t] = (g >= 0 && g < NN) ? coord[(size_t)b * NN + g] : 0.f;
  }
  __syncthreads();

  // ---- G1 (MFMA): B = sH(80 rows) @ msg_w1[128:256] -> sBf fp32 ----
  if (wm == 0) {
    v4f acc[3][2];
#pragma unroll
    for (int mt = 0; mt < 3; ++mt)
#pragma unroll
      for (int nt = 0; nt < 2; ++nt) acc[mt][nt] = (v4f){0.f, 0.f, 0.f, 0.f};
    mgemm<3>(sHhi, sHlo, msg_w1 + 128 * HD, 0, wn, l15, quad, acc);
#pragma unroll
    for (int mt = 0; mt < 3; ++mt)
#pragma unroll
      for (int nt = 0; nt < 2; ++nt)
#pragma unroll
        for (int rg = 0; rg < 4; ++rg)
          sBf[(mt * 16 + quad * 4 + rg) * PB + wn * 32 + nt * 16 + l15] = acc[mt][nt][rg];
  } else {
    v4f acc[2][2];
#pragma unroll
    for (int mt = 0; mt < 2; ++mt)
#pragma unroll
      for (int nt = 0; nt < 2; ++nt) acc[mt][nt] = (v4f){0.f, 0.f, 0.f, 0.f};
    mgemm<2>(sHhi, sHlo, msg_w1 + 128 * HD, 48, wn, l15, quad, acc);
#pragma unroll
    for (int mt = 0; mt < 2; ++mt)
#pragma unroll
      for (int nt = 0; nt < 2; ++nt)
#pragma unroll
        for (int rg = 0; rg < 4; ++rg)
          sBf[(48 + mt * 16 + quad * 4 + rg) * PB + wn * 32 + nt * 16 + l15] = acc[mt][nt][rg];
  }
  // ---- G2 (MFMA): A = sH(tile rows) @ msg_w1[0:128] + b1 -> P1 planes ----
  {
    v4f acc[2][2];
#pragma unroll
    for (int mt = 0; mt < 2; ++mt)
#pragma unroll
      for (int nt = 0; nt < 2; ++nt) acc[mt][nt] = (v4f){0.f, 0.f, 0.f, 0.f};
    mgemm<2>(sHhi, sHlo, msg_w1, HALO + wm * 32, wn, l15, quad, acc);
    float bv0 = msg_b1[col0], bv1 = msg_b1[col1];
#pragma unroll
    for (int mt = 0; mt < 2; ++mt)
#pragma unroll
      for (int nt = 0; nt < 2; ++nt)
#pragma unroll
        for (int rg = 0; rg < 4; ++rg)
          wr_pair(sP1hi, sP1lo,
                  (wm * 32 + mt * 16 + quad * 4 + rg) * PP + wn * 32 + nt * 16 + l15,
                  acc[mt][nt][rg] + (nt ? bv1 : bv0));
  }
  __syncthreads();

  // ---- MSG: s_i = (1/cnt) * sum silu(A_i + B_j + dc*w1_last) -> P2 planes ----
  {
    const int c = t & 127;
    const int grp = t >> 7;   // 0..3 -> rows grp*16 .. grp*16+15
    const float wl = msg_w1[256 * HD + c];
    for (int rr = 0; rr < 16; ++rr) {
      const int r = grp * 16 + rr;
      const int i = n0 + r;
      const float a = b2f((unsigned short)sP1hi[r * PP + c]) + b2f((unsigned short)sP1lo[r * PP + c]);
      const float ci = sC[r + HALO];
      float s = 0.f;
#pragma unroll
      for (int d = -HALO; d <= HALO; ++d) {
        if (d == 0) continue;
        const int j = i + d;
        if (j >= 0 && j < NN) {
          const int rj = r + HALO + d;
          const float z = a + sBf[rj * PB + c] + (sC[rj] - ci) * wl;
          s += silu_acc(z);
        }
      }
      const int cnt = min(i, HALO) + min(NN - 1 - i, HALO);
      wr_pair(sP2hi, sP2lo, r * PP + c, s / (float)cnt);
    }
  }
  __syncthreads();

  // ---- G3 (MFMA): agg = P2(s) @ msg_w2 + b2 -> P1 planes (A dead; disjoint bufs) ----
  {
    v4f acc[2][2];
#pragma unroll
    for (int mt = 0; mt < 2; ++mt)
#pragma unroll
      for (int nt = 0; nt < 2; ++nt) acc[mt][nt] = (v4f){0.f, 0.f, 0.f, 0.f};
    mgemm<2>(sP2hi, sP2lo, msg_w2, wm * 32, wn, l15, quad, acc);
    float bv0 = msg_b2[col0], bv1 = msg_b2[col1];
#pragma unroll
    for (int mt = 0; mt < 2; ++mt)
#pragma unroll
      for (int nt = 0; nt < 2; ++nt)
#pragma unroll
        for (int rg = 0; rg < 4; ++rg)
          wr_pair(sP1hi, sP1lo,
                  (wm * 32 + mt * 16 + quad * 4 + rg) * PP + wn * 32 + nt * 16 + l15,
                  acc[mt][nt][rg] + (nt ? bv1 : bv0));
  }
  __syncthreads();

  // ---- G4 (MFMA): t = silu(sH@upd_w1[0:128] + P1(agg)@upd_w1[128:256] + ub1) -> P2 ----
  {
    v4f acc[2][2];
#pragma unroll
    for (int mt = 0; mt < 2; ++mt)
#pragma unroll
      for (int nt = 0; nt < 2; ++nt) acc[mt][nt] = (v4f){0.f, 0.f, 0.f, 0.f};
    mgemm<2>(sHhi, sHlo, upd_w1, HALO + wm * 32, wn, l15, quad, acc);
    mgemm<2>(sP1hi, sP1lo, upd_w1 + 128 * HD, wm * 32, wn, l15, quad, acc);
    float bv0 = upd_b1[col0], bv1 = upd_b1[col1];
#pragma unroll
    for (int mt = 0; mt < 2; ++mt)
#pragma unroll
      for (int nt = 0; nt < 2; ++nt)
#pragma unroll
        for (int rg = 0; rg < 4; ++rg)
          wr_pair(sP2hi, sP2lo,
                  (wm * 32 + mt * 16 + quad * 4 + rg) * PP + wn * 32 + nt * 16 + l15,
                  silu_acc(acc[mt][nt][rg] + (nt ? bv1 : bv0)));
  }
  __syncthreads();

  // ---- G5 (MFMA): dh = P2(t) @ upd_w2 + ub2 -> sBf fp32 rows 0..63 (B dead) ----
  {
    v4f acc[2][2];
#pragma unroll
    for (int mt = 0; mt < 2; ++mt)
#pragma unroll
      for (int nt = 0; nt < 2; ++nt) acc[mt][nt] = (v4f){0.f, 0.f, 0.f, 0.f};
    mgemm<2>(sP2hi, sP2lo, upd_w2, wm * 32, wn, l15, quad, acc);
    float bv0 = upd_b2[col0], bv1 = upd_b2[col1];
#pragma unroll
    for (int mt = 0; mt < 2; ++mt)
#pragma unroll
      for (int nt = 0; nt < 2; ++nt)
#pragma unroll
        for (int rg = 0; rg < 4; ++rg)
          sBf[(wm * 32 + mt * 16 + quad * 4 + rg) * PB + wn * 32 + nt * 16 + l15] =
              acc[mt][nt][rg] + (nt ? bv1 : bv0);
  }
  __syncthreads();

  // ---- LN: x = h + dh; out = (x-mu)*rstd*g + b ----
  {
    const int r = t >> 3;       // 0..63
    const int part = t & 7;     // 0..7
    const int c0 = part * 16;
    const float* hrow = h + hb + (size_t)r * HD + c0;
    float xs[16];
    float s1 = 0.f, s2 = 0.f;
#pragma unroll
    for (int q = 0; q < 4; ++q) {
      float4 hv = *(const float4*)(hrow + q * 4);
      float4 dv = *(const float4*)&sBf[r * PB + c0 + q * 4];
      float x0 = hv.x + dv.x, x1 = hv.y + dv.y, x2 = hv.z + dv.z, x3 = hv.w + dv.w;
      xs[q * 4 + 0] = x0; xs[q * 4 + 1] = x1; xs[q * 4 + 2] = x2; xs[q * 4 + 3] = x3;
      s1 += x0 + x1 + x2 + x3;
      s2 += x0 * x0 + x1 * x1 + x2 * x2 + x3 * x3;
    }
    s1 += __shfl_xor(s1, 1); s2 += __shfl_xor(s2, 1);
    s1 += __shfl_xor(s1, 2); s2 += __shfl_xor(s2, 2);
    s1 += __shfl_xor(s1, 4); s2 += __shfl_xor(s2, 4);
    float mean = s1 * (1.0f / 128.0f);
    float var = s2 * (1.0f / 128.0f) - mean * mean;
    float rstd = rsqrtf(fmaxf(var, 0.f) + 1e-5f);
    float* orow = out + hb + (size_t)r * HD + c0;
#pragma unroll
    for (int q = 0; q < 4; ++q) {
      float4 gv = *(const float4*)(ln_g + c0 + q * 4);
      float4 bv = *(const float4*)(ln_b + c0 + q * 4);
      float4 ov;
      ov.x = (xs[q * 4 + 0] - mean) * rstd * gv.x + bv.x;
      ov.y = (xs[q * 4 + 1] - mean) * rstd * gv.y + bv.y;
      ov.z = (xs[q * 4 + 2] - mean) * rstd * gv.z + bv.z;
      ov.w = (xs[q * 4 + 3] - mean) * rstd * gv.w + bv.w;
      *(float4*)(orow + q * 4) = ov;
    }
  }
}

extern "C" void kernel_launch(void* const* d_in, const int* in_sizes, int n_in,
                              void* d_out, int out_size, void* d_ws, size_t ws_size,
                              hipStream_t stream) {
  const float* h      = (const float*)d_in[0];
  const float* coord  = (const float*)d_in[1];
  const float* msg_w1 = (const float*)d_in[2];
  const float* msg_b1 = (const float*)d_in[3];
  const float* msg_w2 = (const float*)d_in[4];
  const float* msg_b2 = (const float*)d_in[5];
  const float* upd_w1 = (const float*)d_in[6];
  const float* upd_b1 = (const float*)d_in[7];
  const float* upd_w2 = (const float*)d_in[8];
  const float* upd_b2 = (const float*)d_in[9];
  const float* ln_g   = (const float*)d_in[10];
  const float* ln_b   = (const float*)d_in[11];

  gno_mfma<<<NB * (NN / TILE), 512, 0, stream>>>(
      h, coord, msg_w1, msg_b1, msg_w2, msg_b2, upd_w1, upd_b1, upd_w2, upd_b2,
      ln_g, ln_b, (float*)d_out);
}

// Round 8
// 441.191 us; speedup vs baseline: 2.0863x; 1.1954x over previous
//
// Round 8: round-7 structure UNCHANGED (TILE=64/512t, pre-split X planes).
// Two VALU-throughput fixes:
//  1) split via hardware v_cvt_pk_bf16_f32 (RNE, bit-identical to f2b trick)
//  2) fast silu: v_exp_f32 + v_rcp_f32 (rel err ~1e-6, margin is 7x)
#include <hip/hip_runtime.h>
#include <math.h>

#define NN    16384
#define NB    8
#define HD    128
#define TILE  64
#define HALO  6
#define RWS   76      // TILE + 2*HALO (valid rows)
#define RWSP  80      // padded to 5 m-tiles of 16
#define PP    136     // bf16-plane pitch in shorts: 272 B/row, 16B-aligned
#define PB    132     // fp32 pitch (528 B = 16B-aligned)

typedef short v8s __attribute__((ext_vector_type(8)));
typedef float v4f __attribute__((ext_vector_type(4)));

__device__ __forceinline__ unsigned short f2b(float x) {
  union { float f; unsigned u; } v; v.f = x;
  unsigned r = v.u + 0x7FFFu + ((v.u >> 16) & 1u);
  return (unsigned short)(r >> 16);
}
__device__ __forceinline__ float b2f(unsigned short u) {
  union { unsigned u; float f; } v; v.u = ((unsigned)u) << 16; return v.f;
}
// fast silu: v_exp_f32 + v_rcp_f32 (~5 VALU vs ~30 for libm expf + IEEE div).
// rel err ~1e-6; absmax margin is 0.0156 vs threshold 0.106.
__device__ __forceinline__ float silu_f(float z) {
  return z * __frcp_rn(1.0f + __expf(-z));
}
// split a pair via hardware packed cvt (RNE == f2b bit-trick, bit-identical):
// hw = [bf16(b)|bf16(a)], lw = [bf16(b-hi_b)|bf16(a-hi_a)]
__device__ __forceinline__ void split2(float a, float b, unsigned& hw, unsigned& lw) {
  asm("v_cvt_pk_bf16_f32 %0, %1, %2" : "=v"(hw) : "v"(a), "v"(b));
  union { unsigned u; float f; } fa, fb;
  fa.u = hw << 16;           // b2f of lo16 (= hi part of a)
  fb.u = hw & 0xFFFF0000u;   // b2f of hi16 (= hi part of b)
  float ra = a - fa.f, rb = b - fb.f;
  asm("v_cvt_pk_bf16_f32 %0, %1, %2" : "=v"(lw) : "v"(ra), "v"(rb));
}
// split 8 fp32 -> bf16 hi + bf16 residual lo (x ~= hi + lo, rel err ~2^-17)
__device__ __forceinline__ void split8(const float* p, v8s& hi, v8s& lo) {
  unsigned* hw = (unsigned*)&hi;
  unsigned* lw = (unsigned*)&lo;
#pragma unroll
  for (int q = 0; q < 4; ++q) split2(p[2 * q], p[2 * q + 1], hw[q], lw[q]);
}
// split value -> hi/lo planes (scalar path, unchanged bits)
__device__ __forceinline__ void wr_pair(short* hiP, short* loP, int idx, float v) {
  unsigned short hb = f2b(v);
  hiP[idx] = (short)hb;
  loP[idx] = (short)f2b(v - b2f(hb));
}

// MFMA GEMM, bf16x3 (fp32-quality): acc[mt][nt] += X[moff+mt*16+m][:] @ W[:][n]
// X: pre-split bf16 hi/lo planes in LDS (pitch PP) -> 2x ds_read_b128, no conversion.
// W: fp32 in GLOBAL, row-major [128][128], split on the fly (cvt_pk path).
template<int MT>
__device__ __forceinline__ void mgemm(const short* Xhi, const short* Xlo,
                                      const float* __restrict__ W,
                                      int moff, int wn, int l15, int quad, v4f acc[][2]) {
  const int k0q = quad * 8;
  v8s whi[2][4], wlo[2][4];
#pragma unroll
  for (int nt = 0; nt < 2; ++nt) {
    const int n = wn * 32 + nt * 16 + l15;
#pragma unroll
    for (int ks = 0; ks < 4; ++ks) {
      float wv[8];
#pragma unroll
      for (int j = 0; j < 8; ++j) wv[j] = W[(ks * 32 + k0q + j) * HD + n];
      split8(wv, whi[nt][ks], wlo[nt][ks]);
    }
  }
#pragma unroll
  for (int ks = 0; ks < 4; ++ks) {
#pragma unroll
    for (int mt = 0; mt < MT; ++mt) {
      const int xo = (moff + mt * 16 + l15) * PP + ks * 32 + k0q;
      v8s ahi = *(const v8s*)&Xhi[xo];
      v8s alo = *(const v8s*)&Xlo[xo];
#pragma unroll
      for (int nt = 0; nt < 2; ++nt) {
        acc[mt][nt] = __builtin_amdgcn_mfma_f32_16x16x32_bf16(ahi, whi[nt][ks], acc[mt][nt], 0, 0, 0);
        acc[mt][nt] = __builtin_amdgcn_mfma_f32_16x16x32_bf16(ahi, wlo[nt][ks], acc[mt][nt], 0, 0, 0);
        acc[mt][nt] = __builtin_amdgcn_mfma_f32_16x16x32_bf16(alo, whi[nt][ks], acc[mt][nt], 0, 0, 0);
      }
    }
  }
}

__global__ __launch_bounds__(512, 2) void gno_mfma(
    const float* __restrict__ h, const float* __restrict__ coord,
    const float* __restrict__ msg_w1, const float* __restrict__ msg_b1,
    const float* __restrict__ msg_w2, const float* __restrict__ msg_b2,
    const float* __restrict__ upd_w1, const float* __restrict__ upd_b1,
    const float* __restrict__ upd_w2, const float* __restrict__ upd_b2,
    const float* __restrict__ ln_g, const float* __restrict__ ln_b,
    float* __restrict__ out) {
  // LDS = 43520 + 42240 + 34816 + 34816 + 320 = 155712 B -> 1 WG/CU, 8 waves
  __shared__ short sHhi[RWSP * PP], sHlo[RWSP * PP];    // h planes (G1,G2,G4)
  __shared__ float sBf[RWSP * PB];                      // B fp32 (G1->MSG), then dh fp32 (G5->LN)
  __shared__ short sP1hi[TILE * PP], sP1lo[TILE * PP];  // A (G2->MSG), then agg (G3->G4)
  __shared__ short sP2hi[TILE * PP], sP2lo[TILE * PP];  // s (MSG->G3), then t (G4->G5)
  __shared__ float sC[RWSP];                            // coord

  const int t = threadIdx.x;
  const int wave = t >> 6, lane = t & 63, l15 = lane & 15, quad = lane >> 4;
  const int wn = wave & 3;            // column group: cols [wn*32, wn*32+32)
  const int wm = wave >> 2;           // row group: rows [wm*32, wm*32+32) of the tile
  const int b = blockIdx.x / (NN / TILE);
  const int n0 = (blockIdx.x % (NN / TILE)) * TILE;
  const size_t hb = ((size_t)b * NN + n0) * HD;
  const int col0 = wn * 32 + l15, col1 = col0 + 16;

  // ---- stage h: split to bf16 hi/lo planes once (cvt_pk); zero-fill OOB rows ----
  for (int e = t; e < RWSP * HD / 4; e += 512) {  // 2560 quads, 5 iters
    const int r = e >> 5, c4 = (e & 31) << 2;
    const int g = n0 - HALO + r;
    float4 v = {0.f, 0.f, 0.f, 0.f};
    if (g >= 0 && g < NN) v = *(const float4*)&h[((size_t)b * NN + g) * HD + c4];
    unsigned h01, l01, h23, l23;
    split2(v.x, v.y, h01, l01);
    split2(v.z, v.w, h23, l23);
    *(uint2*)&sHhi[r * PP + c4] = make_uint2(h01, h23);
    *(uint2*)&sHlo[r * PP + c4] = make_uint2(l01, l23);
  }
  if (t < RWSP) {
    const int g = n0 - HALO + t;
    sC[t] = (g >= 0 && g < NN) ? coord[(size_t)b * NN + g] : 0.f;
  }
  __syncthreads();

  // ---- G1 (MFMA): B = sH(80 rows) @ msg_w1[128:256] -> sBf fp32 ----
  if (wm == 0) {
    v4f acc[3][2];
#pragma unroll
    for (int mt = 0; mt < 3; ++mt)
#pragma unroll
      for (int nt = 0; nt < 2; ++nt) acc[mt][nt] = (v4f){0.f, 0.f, 0.f, 0.f};
    mgemm<3>(sHhi, sHlo, msg_w1 + 128 * HD, 0, wn, l15, quad, acc);
#pragma unroll
    for (int mt = 0; mt < 3; ++mt)
#pragma unroll
      for (int nt = 0; nt < 2; ++nt)
#pragma unroll
        for (int rg = 0; rg < 4; ++rg)
          sBf[(mt * 16 + quad * 4 + rg) * PB + wn * 32 + nt * 16 + l15] = acc[mt][nt][rg];
  } else {
    v4f acc[2][2];
#pragma unroll
    for (int mt = 0; mt < 2; ++mt)
#pragma unroll
      for (int nt = 0; nt < 2; ++nt) acc[mt][nt] = (v4f){0.f, 0.f, 0.f, 0.f};
    mgemm<2>(sHhi, sHlo, msg_w1 + 128 * HD, 48, wn, l15, quad, acc);
#pragma unroll
    for (int mt = 0; mt < 2; ++mt)
#pragma unroll
      for (int nt = 0; nt < 2; ++nt)
#pragma unroll
        for (int rg = 0; rg < 4; ++rg)
          sBf[(48 + mt * 16 + quad * 4 + rg) * PB + wn * 32 + nt * 16 + l15] = acc[mt][nt][rg];
  }
  // ---- G2 (MFMA): A = sH(tile rows) @ msg_w1[0:128] + b1 -> P1 planes ----
  {
    v4f acc[2][2];
#pragma unroll
    for (int mt = 0; mt < 2; ++mt)
#pragma unroll
      for (int nt = 0; nt < 2; ++nt) acc[mt][nt] = (v4f){0.f, 0.f, 0.f, 0.f};
    mgemm<2>(sHhi, sHlo, msg_w1, HALO + wm * 32, wn, l15, quad, acc);
    float bv0 = msg_b1[col0], bv1 = msg_b1[col1];
#pragma unroll
    for (int mt = 0; mt < 2; ++mt)
#pragma unroll
      for (int nt = 0; nt < 2; ++nt)
#pragma unroll
        for (int rg = 0; rg < 4; ++rg)
          wr_pair(sP1hi, sP1lo,
                  (wm * 32 + mt * 16 + quad * 4 + rg) * PP + wn * 32 + nt * 16 + l15,
                  acc[mt][nt][rg] + (nt ? bv1 : bv0));
  }
  __syncthreads();

  // ---- MSG: s_i = (1/cnt) * sum silu(A_i + B_j + dc*w1_last) -> P2 planes ----
  {
    const int c = t & 127;
    const int grp = t >> 7;   // 0..3 -> rows grp*16 .. grp*16+15
    const float wl = msg_w1[256 * HD + c];
    for (int rr = 0; rr < 16; ++rr) {
      const int r = grp * 16 + rr;
      const int i = n0 + r;
      const float a = b2f((unsigned short)sP1hi[r * PP + c]) + b2f((unsigned short)sP1lo[r * PP + c]);
      const float ci = sC[r + HALO];
      float s = 0.f;
#pragma unroll
      for (int d = -HALO; d <= HALO; ++d) {
        if (d == 0) continue;
        const int j = i + d;
        if (j >= 0 && j < NN) {
          const int rj = r + HALO + d;
          const float z = a + sBf[rj * PB + c] + (sC[rj] - ci) * wl;
          s += silu_f(z);
        }
      }
      const int cnt = min(i, HALO) + min(NN - 1 - i, HALO);
      wr_pair(sP2hi, sP2lo, r * PP + c, s / (float)cnt);
    }
  }
  __syncthreads();

  // ---- G3 (MFMA): agg = P2(s) @ msg_w2 + b2 -> P1 planes (A dead; disjoint bufs) ----
  {
    v4f acc[2][2];
#pragma unroll
    for (int mt = 0; mt < 2; ++mt)
#pragma unroll
      for (int nt = 0; nt < 2; ++nt) acc[mt][nt] = (v4f){0.f, 0.f, 0.f, 0.f};
    mgemm<2>(sP2hi, sP2lo, msg_w2, wm * 32, wn, l15, quad, acc);
    float bv0 = msg_b2[col0], bv1 = msg_b2[col1];
#pragma unroll
    for (int mt = 0; mt < 2; ++mt)
#pragma unroll
      for (int nt = 0; nt < 2; ++nt)
#pragma unroll
        for (int rg = 0; rg < 4; ++rg)
          wr_pair(sP1hi, sP1lo,
                  (wm * 32 + mt * 16 + quad * 4 + rg) * PP + wn * 32 + nt * 16 + l15,
                  acc[mt][nt][rg] + (nt ? bv1 : bv0));
  }
  __syncthreads();

  // ---- G4 (MFMA): t = silu(sH@upd_w1[0:128] + P1(agg)@upd_w1[128:256] + ub1) -> P2 ----
  {
    v4f acc[2][2];
#pragma unroll
    for (int mt = 0; mt < 2; ++mt)
#pragma unroll
      for (int nt = 0; nt < 2; ++nt) acc[mt][nt] = (v4f){0.f, 0.f, 0.f, 0.f};
    mgemm<2>(sHhi, sHlo, upd_w1, HALO + wm * 32, wn, l15, quad, acc);
    mgemm<2>(sP1hi, sP1lo, upd_w1 + 128 * HD, wm * 32, wn, l15, quad, acc);
    float bv0 = upd_b1[col0], bv1 = upd_b1[col1];
#pragma unroll
    for (int mt = 0; mt < 2; ++mt)
#pragma unroll
      for (int nt = 0; nt < 2; ++nt)
#pragma unroll
        for (int rg = 0; rg < 4; ++rg)
          wr_pair(sP2hi, sP2lo,
                  (wm * 32 + mt * 16 + quad * 4 + rg) * PP + wn * 32 + nt * 16 + l15,
                  silu_f(acc[mt][nt][rg] + (nt ? bv1 : bv0)));
  }
  __syncthreads();

  // ---- G5 (MFMA): dh = P2(t) @ upd_w2 + ub2 -> sBf fp32 rows 0..63 (B dead) ----
  {
    v4f acc[2][2];
#pragma unroll
    for (int mt = 0; mt < 2; ++mt)
#pragma unroll
      for (int nt = 0; nt < 2; ++nt) acc[mt][nt] = (v4f){0.f, 0.f, 0.f, 0.f};
    mgemm<2>(sP2hi, sP2lo, upd_w2, wm * 32, wn, l15, quad, acc);
    float bv0 = upd_b2[col0], bv1 = upd_b2[col1];
#pragma unroll
    for (int mt = 0; mt < 2; ++mt)
#pragma unroll
      for (int nt = 0; nt < 2; ++nt)
#pragma unroll
        for (int rg = 0; rg < 4; ++rg)
          sBf[(wm * 32 + mt * 16 + quad * 4 + rg) * PB + wn * 32 + nt * 16 + l15] =
              acc[mt][nt][rg] + (nt ? bv1 : bv0);
  }
  __syncthreads();

  // ---- LN: x = h + dh; out = (x-mu)*rstd*g + b ----
  {
    const int r = t >> 3;       // 0..63
    const int part = t & 7;     // 0..7
    const int c0 = part * 16;
    const float* hrow = h + hb + (size_t)r * HD + c0;
    float xs[16];
    float s1 = 0.f, s2 = 0.f;
#pragma unroll
    for (int q = 0; q < 4; ++q) {
      float4 hv = *(const float4*)(hrow + q * 4);
      float4 dv = *(const float4*)&sBf[r * PB + c0 + q * 4];
      float x0 = hv.x + dv.x, x1 = hv.y + dv.y, x2 = hv.z + dv.z, x3 = hv.w + dv.w;
      xs[q * 4 + 0] = x0; xs[q * 4 + 1] = x1; xs[q * 4 + 2] = x2; xs[q * 4 + 3] = x3;
      s1 += x0 + x1 + x2 + x3;
      s2 += x0 * x0 + x1 * x1 + x2 * x2 + x3 * x3;
    }
    s1 += __shfl_xor(s1, 1); s2 += __shfl_xor(s2, 1);
    s1 += __shfl_xor(s1, 2); s2 += __shfl_xor(s2, 2);
    s1 += __shfl_xor(s1, 4); s2 += __shfl_xor(s2, 4);
    float mean = s1 * (1.0f / 128.0f);
    float var = s2 * (1.0f / 128.0f) - mean * mean;
    float rstd = rsqrtf(fmaxf(var, 0.f) + 1e-5f);
    float* orow = out + hb + (size_t)r * HD + c0;
#pragma unroll
    for (int q = 0; q < 4; ++q) {
      float4 gv = *(const float4*)(ln_g + c0 + q * 4);
      float4 bv = *(const float4*)(ln_b + c0 + q * 4);
      float4 ov;
      ov.x = (xs[q * 4 + 0] - mean) * rstd * gv.x + bv.x;
      ov.y = (xs[q * 4 + 1] - mean) * rstd * gv.y + bv.y;
      ov.z = (xs[q * 4 + 2] - mean) * rstd * gv.z + bv.z;
      ov.w = (xs[q * 4 + 3] - mean) * rstd * gv.w + bv.w;
      *(float4*)(orow + q * 4) = ov;
    }
  }
}

extern "C" void kernel_launch(void* const* d_in, const int* in_sizes, int n_in,
                              void* d_out, int out_size, void* d_ws, size_t ws_size,
                              hipStream_t stream) {
  const float* h      = (const float*)d_in[0];
  const float* coord  = (const float*)d_in[1];
  const float* msg_w1 = (const float*)d_in[2];
  const float* msg_b1 = (const float*)d_in[3];
  const float* msg_w2 = (const float*)d_in[4];
  const float* msg_b2 = (const float*)d_in[5];
  const float* upd_w1 = (const float*)d_in[6];
  const float* upd_b1 = (const float*)d_in[7];
  const float* upd_w2 = (const float*)d_in[8];
  const float* upd_b2 = (const float*)d_in[9];
  const float* ln_g   = (const float*)d_in[10];
  const float* ln_b   = (const float*)d_in[11];

  gno_mfma<<<NB * (NN / TILE), 512, 0, stream>>>(
      h, coord, msg_w1, msg_b1, msg_w2, msg_b2, upd_w1, upd_b1, upd_w2, upd_b2,
      ln_g, ln_b, (float*)d_out);
}

// Round 11
// 417.202 us; speedup vs baseline: 2.2062x; 1.0575x over previous
//
// Round 11: pure-bf16 path (round 10) FORCED to 1 WG/CU.
// Session law (10/10 rounds): 2 co-resident WGs/CU => LDS corruption
// (finite garbage on fp32 buffers, NaN on bf16 buffers); 1 WG/CU => pass.
// sHs padded +16 rows -> LDS 83008 B > 81920 B, so only 1 WG fits per CU.
// Launch bounds restored to the known-good (512, 2).
#include <hip/hip_runtime.h>
#include <math.h>

#define NN    16384
#define NB    8
#define HD    128
#define TILE  64
#define HALO  6
#define RWS   76      // TILE + 2*HALO (valid rows)
#define RWSP  80      // padded to 5 m-tiles of 16
#define HPAD  96      // sHs declared rows: pads LDS past 80 KiB (occupancy clamp)
#define PP    136     // bf16 pitch in shorts: 272 B/row, 16B-aligned

typedef short v8s __attribute__((ext_vector_type(8)));
typedef float v4f __attribute__((ext_vector_type(4)));

__device__ __forceinline__ unsigned short f2b(float x) {   // RNE, == v_cvt_bf16
  union { float f; unsigned u; } v; v.f = x;
  unsigned r = v.u + 0x7FFFu + ((v.u >> 16) & 1u);
  return (unsigned short)(r >> 16);
}
__device__ __forceinline__ float b2f(unsigned short u) {
  union { unsigned u; float f; } v; v.u = ((unsigned)u) << 16; return v.f;
}
// fast silu: v_exp_f32 + v_rcp_f32 (validated round 8)
__device__ __forceinline__ float silu_f(float z) {
  return z * __frcp_rn(1.0f + __expf(-z));
}
// 8 fp32 -> 8 bf16 via 4 hardware packed converts (RNE), union-punned
__device__ __forceinline__ v8s cvt8(const float* p) {
  union { v8s s; unsigned u[4]; } r;
#pragma unroll
  for (int q = 0; q < 4; ++q)
    asm("v_cvt_pk_bf16_f32 %0, %1, %2" : "=v"(r.u[q]) : "v"(p[2 * q]), "v"(p[2 * q + 1]));
  return r.s;
}

// MFMA GEMM, pure bf16: acc[mt][nt] += X[moff+mt*16+m][:] @ W[:][n]
// X: bf16 plane in LDS (pitch PP) -> 1x ds_read_b128 per fragment.
// W: fp32 in GLOBAL, row-major [128][128], cvt on the fly (4 cvt_pk/fragment).
template<int MT>
__device__ __forceinline__ void mgemm(const short* X, const float* __restrict__ W,
                                      int moff, int wn, int l15, int quad, v4f acc[][2]) {
  const int k0q = quad * 8;
  v8s wf[2][4];
#pragma unroll
  for (int nt = 0; nt < 2; ++nt) {
    const int n = wn * 32 + nt * 16 + l15;
#pragma unroll
    for (int ks = 0; ks < 4; ++ks) {
      float wv[8];
#pragma unroll
      for (int j = 0; j < 8; ++j) wv[j] = W[(ks * 32 + k0q + j) * HD + n];
      wf[nt][ks] = cvt8(wv);
    }
  }
#pragma unroll
  for (int ks = 0; ks < 4; ++ks) {
#pragma unroll
    for (int mt = 0; mt < MT; ++mt) {
      const int xo = (moff + mt * 16 + l15) * PP + ks * 32 + k0q;
      v8s a = *(const v8s*)&X[xo];
#pragma unroll
      for (int nt = 0; nt < 2; ++nt)
        acc[mt][nt] = __builtin_amdgcn_mfma_f32_16x16x32_bf16(a, wf[nt][ks], acc[mt][nt], 0, 0, 0);
    }
  }
}

__global__ __launch_bounds__(512, 2) void gno_mfma(
    const float* __restrict__ h, const float* __restrict__ coord,
    const float* __restrict__ msg_w1, const float* __restrict__ msg_b1,
    const float* __restrict__ msg_w2, const float* __restrict__ msg_b2,
    const float* __restrict__ upd_w1, const float* __restrict__ upd_b1,
    const float* __restrict__ upd_w2, const float* __restrict__ upd_b2,
    const float* __restrict__ ln_g, const float* __restrict__ ln_b,
    float* __restrict__ out) {
  // LDS = 26112 + 21760 + 17408 + 17408 + 320 = 83008 B > 81920 -> 1 WG/CU
  __shared__ short sHs[HPAD * PP];   // h bf16 (G1,G2,G4); rows 80..95 = pad only
  __shared__ short sBs[RWSP * PP];   // B bf16 (G1->MSG), then dh bf16 (G5->LN)
  __shared__ short sP1[TILE * PP];   // A (G2->MSG), then agg (G3->G4)
  __shared__ short sP2[TILE * PP];   // s (MSG->G3), then t (G4->G5)
  __shared__ float sC[RWSP];         // coord

  const int t = threadIdx.x;
  const int wave = t >> 6, lane = t & 63, l15 = lane & 15, quad = lane >> 4;
  const int wn = wave & 3;            // column group: cols [wn*32, wn*32+32)
  const int wm = wave >> 2;           // row group: rows [wm*32, wm*32+32) of the tile
  const int b = blockIdx.x / (NN / TILE);
  const int n0 = (blockIdx.x % (NN / TILE)) * TILE;
  const size_t hb = ((size_t)b * NN + n0) * HD;
  const int col0 = wn * 32 + l15, col1 = col0 + 16;

  // ---- defensive zero-init of ALL LDS (barrier-fenced from staging) ----
  for (int e = t; e < HPAD * PP / 2; e += 512) ((int*)sHs)[e] = 0;
  for (int e = t; e < RWSP * PP / 2; e += 512) ((int*)sBs)[e] = 0;
  for (int e = t; e < TILE * PP / 2; e += 512) {
    ((int*)sP1)[e] = 0; ((int*)sP2)[e] = 0;
  }
  __syncthreads();

  // ---- stage h -> bf16 plane (hardware cvt_pk); zero-fill OOB rows ----
  for (int e = t; e < RWSP * HD / 4; e += 512) {  // 2560 quads, 5 iters
    const int r = e >> 5, c4 = (e & 31) << 2;
    const int g = n0 - HALO + r;
    float4 v = {0.f, 0.f, 0.f, 0.f};
    if (g >= 0 && g < NN) v = *(const float4*)&h[((size_t)b * NN + g) * HD + c4];
    unsigned h01, h23;
    asm("v_cvt_pk_bf16_f32 %0, %1, %2" : "=v"(h01) : "v"(v.x), "v"(v.y));
    asm("v_cvt_pk_bf16_f32 %0, %1, %2" : "=v"(h23) : "v"(v.z), "v"(v.w));
    *(uint2*)&sHs[r * PP + c4] = make_uint2(h01, h23);
  }
  if (t < RWSP) {
    const int g = n0 - HALO + t;
    sC[t] = (g >= 0 && g < NN) ? coord[(size_t)b * NN + g] : 0.f;
  }
  __syncthreads();

  // ---- G1 (MFMA): B = sH(80 rows) @ msg_w1[128:256] -> sBs bf16 ----
  if (wm == 0) {
    v4f acc[3][2];
#pragma unroll
    for (int mt = 0; mt < 3; ++mt)
#pragma unroll
      for (int nt = 0; nt < 2; ++nt) acc[mt][nt] = (v4f){0.f, 0.f, 0.f, 0.f};
    mgemm<3>(sHs, msg_w1 + 128 * HD, 0, wn, l15, quad, acc);
#pragma unroll
    for (int mt = 0; mt < 3; ++mt)
#pragma unroll
      for (int nt = 0; nt < 2; ++nt)
#pragma unroll
        for (int rg = 0; rg < 4; ++rg)
          sBs[(mt * 16 + quad * 4 + rg) * PP + wn * 32 + nt * 16 + l15] =
              (short)f2b(acc[mt][nt][rg]);
  } else {
    v4f acc[2][2];
#pragma unroll
    for (int mt = 0; mt < 2; ++mt)
#pragma unroll
      for (int nt = 0; nt < 2; ++nt) acc[mt][nt] = (v4f){0.f, 0.f, 0.f, 0.f};
    mgemm<2>(sHs, msg_w1 + 128 * HD, 48, wn, l15, quad, acc);
#pragma unroll
    for (int mt = 0; mt < 2; ++mt)
#pragma unroll
      for (int nt = 0; nt < 2; ++nt)
#pragma unroll
        for (int rg = 0; rg < 4; ++rg)
          sBs[(48 + mt * 16 + quad * 4 + rg) * PP + wn * 32 + nt * 16 + l15] =
              (short)f2b(acc[mt][nt][rg]);
  }
  // ---- G2 (MFMA): A = sH(tile rows) @ msg_w1[0:128] + b1 -> sP1 bf16 ----
  {
    v4f acc[2][2];
#pragma unroll
    for (int mt = 0; mt < 2; ++mt)
#pragma unroll
      for (int nt = 0; nt < 2; ++nt) acc[mt][nt] = (v4f){0.f, 0.f, 0.f, 0.f};
    mgemm<2>(sHs, msg_w1, HALO + wm * 32, wn, l15, quad, acc);
    float bv0 = msg_b1[col0], bv1 = msg_b1[col1];
#pragma unroll
    for (int mt = 0; mt < 2; ++mt)
#pragma unroll
      for (int nt = 0; nt < 2; ++nt)
#pragma unroll
        for (int rg = 0; rg < 4; ++rg)
          sP1[(wm * 32 + mt * 16 + quad * 4 + rg) * PP + wn * 32 + nt * 16 + l15] =
              (short)f2b(acc[mt][nt][rg] + (nt ? bv1 : bv0));
  }
  __syncthreads();

  // ---- MSG: s_i = (1/cnt) * sum silu(A_i + B_j + dc*w1_last) -> sP2 bf16 ----
  {
    const int c = t & 127;
    const int grp = t >> 7;   // 0..3 -> rows grp*16 .. grp*16+15
    const float wl = msg_w1[256 * HD + c];
    for (int rr = 0; rr < 16; ++rr) {
      const int r = grp * 16 + rr;
      const int i = n0 + r;
      const float a = b2f((unsigned short)sP1[r * PP + c]);
      const float ci = sC[r + HALO];
      float s = 0.f;
#pragma unroll
      for (int d = -HALO; d <= HALO; ++d) {
        if (d == 0) continue;
        const int j = i + d;
        if (j >= 0 && j < NN) {
          const int rj = r + HALO + d;
          const float z = a + b2f((unsigned short)sBs[rj * PP + c]) + (sC[rj] - ci) * wl;
          s += silu_f(z);
        }
      }
      const int cnt = min(i, HALO) + min(NN - 1 - i, HALO);
      sP2[r * PP + c] = (short)f2b(s / (float)cnt);
    }
  }
  __syncthreads();

  // ---- G3 (MFMA): agg = P2(s) @ msg_w2 + b2 -> sP1 (A dead) ----
  {
    v4f acc[2][2];
#pragma unroll
    for (int mt = 0; mt < 2; ++mt)
#pragma unroll
      for (int nt = 0; nt < 2; ++nt) acc[mt][nt] = (v4f){0.f, 0.f, 0.f, 0.f};
    mgemm<2>(sP2, msg_w2, wm * 32, wn, l15, quad, acc);
    float bv0 = msg_b2[col0], bv1 = msg_b2[col1];
#pragma unroll
    for (int mt = 0; mt < 2; ++mt)
#pragma unroll
      for (int nt = 0; nt < 2; ++nt)
#pragma unroll
        for (int rg = 0; rg < 4; ++rg)
          sP1[(wm * 32 + mt * 16 + quad * 4 + rg) * PP + wn * 32 + nt * 16 + l15] =
              (short)f2b(acc[mt][nt][rg] + (nt ? bv1 : bv0));
  }
  __syncthreads();

  // ---- G4 (MFMA): t = silu(sH@upd_w1[0:128] + P1(agg)@upd_w1[128:256] + ub1) -> sP2 ----
  {
    v4f acc[2][2];
#pragma unroll
    for (int mt = 0; mt < 2; ++mt)
#pragma unroll
      for (int nt = 0; nt < 2; ++nt) acc[mt][nt] = (v4f){0.f, 0.f, 0.f, 0.f};
    mgemm<2>(sHs, upd_w1, HALO + wm * 32, wn, l15, quad, acc);
    mgemm<2>(sP1, upd_w1 + 128 * HD, wm * 32, wn, l15, quad, acc);
    float bv0 = upd_b1[col0], bv1 = upd_b1[col1];
#pragma unroll
    for (int mt = 0; mt < 2; ++mt)
#pragma unroll
      for (int nt = 0; nt < 2; ++nt)
#pragma unroll
        for (int rg = 0; rg < 4; ++rg)
          sP2[(wm * 32 + mt * 16 + quad * 4 + rg) * PP + wn * 32 + nt * 16 + l15] =
              (short)f2b(silu_f(acc[mt][nt][rg] + (nt ? bv1 : bv0)));
  }
  __syncthreads();

  // ---- G5 (MFMA): dh = P2(t) @ upd_w2 + ub2 -> sBs bf16 rows 0..63 (B dead) ----
  {
    v4f acc[2][2];
#pragma unroll
    for (int mt = 0; mt < 2; ++mt)
#pragma unroll
      for (int nt = 0; nt < 2; ++nt) acc[mt][nt] = (v4f){0.f, 0.f, 0.f, 0.f};
    mgemm<2>(sP2, upd_w2, wm * 32, wn, l15, quad, acc);
    float bv0 = upd_b2[col0], bv1 = upd_b2[col1];
#pragma unroll
    for (int mt = 0; mt < 2; ++mt)
#pragma unroll
      for (int nt = 0; nt < 2; ++nt)
#pragma unroll
        for (int rg = 0; rg < 4; ++rg)
          sBs[(wm * 32 + mt * 16 + quad * 4 + rg) * PP + wn * 32 + nt * 16 + l15] =
              (short)f2b(acc[mt][nt][rg] + (nt ? bv1 : bv0));
  }
  __syncthreads();

  // ---- LN: x = h + dh; out = (x-mu)*rstd*g + b ----
  {
    const int r = t >> 3;       // 0..63
    const int part = t & 7;     // 0..7
    const int c0 = part * 16;
    const float* hrow = h + hb + (size_t)r * HD + c0;
    float xs[16];
    float s1 = 0.f, s2 = 0.f;
#pragma unroll
    for (int q = 0; q < 4; ++q) {
      float4 hv = *(const float4*)(hrow + q * 4);
      short4 dv = *(const short4*)&sBs[r * PP + c0 + q * 4];
      float x0 = hv.x + b2f((unsigned short)dv.x);
      float x1 = hv.y + b2f((unsigned short)dv.y);
      float x2 = hv.z + b2f((unsigned short)dv.z);
      float x3 = hv.w + b2f((unsigned short)dv.w);
      xs[q * 4 + 0] = x0; xs[q * 4 + 1] = x1; xs[q * 4 + 2] = x2; xs[q * 4 + 3] = x3;
      s1 += x0 + x1 + x2 + x3;
      s2 += x0 * x0 + x1 * x1 + x2 * x2 + x3 * x3;
    }
    s1 += __shfl_xor(s1, 1); s2 += __shfl_xor(s2, 1);
    s1 += __shfl_xor(s1, 2); s2 += __shfl_xor(s2, 2);
    s1 += __shfl_xor(s1, 4); s2 += __shfl_xor(s2, 4);
    float mean = s1 * (1.0f / 128.0f);
    float var = s2 * (1.0f / 128.0f) - mean * mean;
    float rstd = rsqrtf(fmaxf(var, 0.f) + 1e-5f);
    float* orow = out + hb + (size_t)r * HD + c0;
#pragma unroll
    for (int q = 0; q < 4; ++q) {
      float4 gv = *(const float4*)(ln_g + c0 + q * 4);
      float4 bv = *(const float4*)(ln_b + c0 + q * 4);
      float4 ov;
      ov.x = (xs[q * 4 + 0] - mean) * rstd * gv.x + bv.x;
      ov.y = (xs[q * 4 + 1] - mean) * rstd * gv.y + bv.y;
      ov.z = (xs[q * 4 + 2] - mean) * rstd * gv.z + bv.z;
      ov.w = (xs[q * 4 + 3] - mean) * rstd * gv.w + bv.w;
      *(float4*)(orow + q * 4) = ov;
    }
  }
}

extern "C" void kernel_launch(void* const* d_in, const int* in_sizes, int n_in,
                              void* d_out, int out_size, void* d_ws, size_t ws_size,
                              hipStream_t stream) {
  const float* h      = (const float*)d_in[0];
  const float* coord  = (const float*)d_in[1];
  const float* msg_w1 = (const float*)d_in[2];
  const float* msg_b1 = (const float*)d_in[3];
  const float* msg_w2 = (const float*)d_in[4];
  const float* msg_b2 = (const float*)d_in[5];
  const float* upd_w1 = (const float*)d_in[6];
  const float* upd_b1 = (const float*)d_in[7];
  const float* upd_w2 = (const float*)d_in[8];
  const float* upd_b2 = (const float*)d_in[9];
  const float* ln_g   = (const float*)d_in[10];
  const float* ln_b   = (const float*)d_in[11];

  gno_mfma<<<NB * (NN / TILE), 512, 0, stream>>>(
      h, coord, msg_w1, msg_b1, msg_w2, msg_b2, upd_w1, upd_b1, upd_w2, upd_b2,
      ln_g, ln_b, (float*)d_out);
}